// Round 10
// baseline (131.903 us; speedup 1.0000x reference)
//
#include <hip/hip_runtime.h>
#include <hip/hip_fp16.h>

// SelfSimilarityProbDistance: tsm[i][j] = mean_{p,q} softplus(a*|X[i,p]-X[j,q]| - b)
// then masked row-softmax of -tsm/TEMP over the valid 448x448 block.
//
// R10 = R9 with the compile fix: cvt_pkrtz returns __fp16-vector, which won't
// implicitly convert to _Float16-vector; use __floats2half2_rn + memcpy bit-cast
// (same v_cvt_pkrtz_f16_f32 after opt).
// R9 plan: 3 kernels -> 2 (softmax fused into eval via threadfence+counter,
// last strip-block does the epilogue; logits in [-4.9,-1.5] so no max-subtract),
// eval lerp via v_dot2_f32_f16 ((G0,dG) . (1,frac) + acc in one instr).

#define NTOT 512
#define NV   448
#define DF   64
#define TEMPC 13.544f
#define NG   512
#define TLO  (-6.0f)
#define GH   (12.0f / 512.0f)
#define GINVH (512.0f / 12.0f)

typedef _Float16 h2 __attribute__((ext_vector_type(2)));

__global__ __launch_bounds__(256) void build_kernel(const float* __restrict__ X,
                                                    unsigned int* __restrict__ tabG,
                                                    float2* __restrict__ idxfrac,
                                                    unsigned int* __restrict__ cnt,
                                                    float* __restrict__ Out,
                                                    float tpar) {
  const int j = blockIdx.x;
  const int tid = threadIdx.x;
  if (j >= NV) {  // invalid output rows: exact zeros (512 floats = 256 float2)
    reinterpret_cast<float2*>(Out + j * NTOT)[tid] = make_float2(0.f, 0.f);
    if (j == NV && tid < 28) cnt[tid] = 0u;   // strip counters (stream-ordered before eval)
    return;
  }
  __shared__ float sy[DF];
  __shared__ float sG[NG + 1];
  if (tid < DF) sy[tid] = X[j * DF + tid];
  __syncthreads();

  // exact G_j at 513 grid points: sum_q max(|v - y_q|, t) via v_max3
  for (int k = tid; k <= NG; k += 256) {
    const float v = TLO + (float)k * GH;
    float acc = 0.f;
#pragma unroll 8
    for (int q = 0; q < DF; ++q) {
      const float d = v - sy[q];
      acc += fmaxf(fmaxf(d, -d), tpar);       // v_max3_f32(d,-d,t)
    }
    sG[k] = acc;
  }
  __syncthreads();

  // pack (G0, G[k+1]-G0) as f16x2
  for (int k = tid; k < NG; k += 256) {
    __half2 h = __floats2half2_rn(sG[k], sG[k + 1] - sG[k]);
    tabG[j * NG + k] = *reinterpret_cast<unsigned int*>(&h);
  }

  // per-feature (idx, packed_f16x2(1.0, frac)) for row j as the i-side
  if (tid < DF) {
    const float x = X[j * DF + tid];
    const float u = (fminf(fmaxf(x, TLO), 6.0f) - TLO) * GINVH;
    int idx = (int)u;
    idx = idx > (NG - 2) ? (NG - 2) : idx;
    const float frac = u - (float)idx;
    __half2 pf = __floats2half2_rn(1.0f, frac);   // (1.0, frac) -> f16x2
    float pf_bits;
    __builtin_memcpy(&pf_bits, &pf, 4);
    idxfrac[j * DF + tid] = make_float2(__int_as_float(idx), pf_bits);
  }
}

__global__ __launch_bounds__(256, 4) void eval_sm_kernel(
    const unsigned int* __restrict__ tabG, const float2* __restrict__ idxfrac,
    float* __restrict__ sums, unsigned int* __restrict__ cnt,
    float* __restrict__ Out, float scale) {
  const int j0 = blockIdx.x * 16;   // 28 x 28 tiles of 16x16 outputs
  const int ib = blockIdx.y;
  const int i0 = ib * 16;

  __shared__ unsigned int sTab[16 * 513];   // 16 j-tables, stride 513 (bank de-alias)
  __shared__ float2 sIF[16][DF];            // i-side (idx, packed(1,frac))

  const int tid = threadIdx.x;
  for (int e = tid; e < 16 * NG; e += 256) {
    const int r = e >> 9, c = e & (NG - 1);
    sTab[r * 513 + c] = tabG[(j0 + r) * NG + c];
  }
  for (int e = tid; e < 16 * DF; e += 256) {
    const int r = e >> 6, c = e & (DF - 1);
    sIF[r][c] = idxfrac[(i0 + r) * DF + c];
  }
  __syncthreads();

  const int tx = tid & 15, ty = tid >> 4;   // output (i0+ty, j0+tx)
  const int tb = tx * 513;
  float acc0 = 0.f, acc1 = 0.f;

#pragma unroll 1
  for (int pc = 0; pc < 4; ++pc) {
    float2 f[16];                            // 16 p's: (idx, packed(1,frac))
#pragma unroll
    for (int k = 0; k < 16; ++k) f[k] = sIF[ty][pc * 16 + k];  // 16-way broadcast
#pragma unroll
    for (int k = 0; k < 16; ++k) {
      const int idx = __float_as_int(f[k].x);
      const unsigned int e = sTab[tb + idx];                   // scattered, de-aliased
      h2 ge, pf;
      __builtin_memcpy(&ge, &e, 4);
      __builtin_memcpy(&pf, &f[k].y, 4);
#if __has_builtin(__builtin_amdgcn_fdot2)
      // G0*1 + dG*frac + acc in ONE v_dot2_f32_f16
      if (k & 1) acc1 = __builtin_amdgcn_fdot2(ge, pf, acc1, false);
      else       acc0 = __builtin_amdgcn_fdot2(ge, pf, acc0, false);
#else
      const float g0 = (float)ge.x, dg = (float)ge.y, fr = (float)pf.y;
      if (k & 1) acc1 += fmaf(fr, dg, g0);
      else       acc0 += fmaf(fr, dg, g0);
#endif
    }
  }
  sums[(i0 + ty) * NTOT + (j0 + tx)] = acc0 + acc1;

  // ---- fused softmax: last block of this 16-row strip does the epilogue ----
  __threadfence();                 // release: sums visible at device scope
  __shared__ int lastFlag;
  if (tid == 0) lastFlag = (atomicAdd(&cnt[ib], 1u) == 27u);
  __syncthreads();
  if (!lastFlag) return;
  __threadfence();                 // acquire: see all 28 blocks' sums

  const int r = tid >> 4, l = tid & 15;     // 16 rows x 16 lanes
  const int row = i0 + r;
  const float* Sr = sums + row * NTOT;
  float e[28];
  float sl = 0.f;
#pragma unroll
  for (int c = 0; c < 28; ++c) {            // cols c*16+l: coalesced 16-lane reads
    e[c] = __builtin_amdgcn_exp2f(Sr[c * 16 + l] * scale);  // |logit|<5: no max needed
    sl += e[c];
  }
#pragma unroll
  for (int m = 1; m <= 8; m <<= 1) sl += __shfl_xor(sl, m);  // 16-lane row reduce
  const float inv = 1.0f / sl;
  float* Or = Out + row * NTOT;
#pragma unroll
  for (int c = 0; c < 28; ++c) Or[c * 16 + l] = e[c] * inv;
#pragma unroll
  for (int c2 = 0; c2 < 4; ++c2) Or[NV + c2 * 16 + l] = 0.f;  // masked cols 448..511
}

extern "C" void kernel_launch(void* const* d_in, const int* in_sizes, int n_in,
                              void* d_out, int out_size, void* d_ws, size_t ws_size,
                              hipStream_t stream) {
  (void)in_sizes; (void)n_in; (void)ws_size; (void)out_size;
  const float* X = (const float*)d_in[0];
  float* Out = (float*)d_out;
  char* ws = (char*)d_ws;

  unsigned int* tabG = (unsigned int*)(ws);                   // 448*512*4 = 896 KB
  float2* idxfrac    = (float2*)(ws + (1u << 20));            // 448*64*8  = 224 KB
  float* sums        = (float*)(ws + (1u << 20) + (1u << 18));// 448*512*4 = 896 KB
  unsigned int* cnt  = (unsigned int*)(ws + (9u << 18));      // 28*4 B @ 2.25 MB

  // a = min(elu(4.0335)+1, 100) = 5.0335; b = 14.0885; mask = arange(512) < 448.
  const double a = 5.0335;
  const double b = 14.0885;
  const double LOG2E = 1.4426950408889634;
  const float tpar = (float)(b / a);   // hinge threshold ~2.799
  // tsm = (a/4096)*S + const; uniform parts cancel in the base-2 softmax:
  const float scale = (float)(-a * LOG2E / (4096.0 * (double)TEMPC));

  build_kernel<<<NTOT, 256, 0, stream>>>(X, tabG, idxfrac, cnt, Out, tpar);
  dim3 grid(NV / 16, NV / 16);
  eval_sm_kernel<<<grid, 256, 0, stream>>>(tabG, idxfrac, sums, cnt, Out, scale);
}

// Round 11
// 70.269 us; speedup vs baseline: 1.8771x; 1.8771x over previous
//
#include <hip/hip_runtime.h>
#include <hip/hip_fp16.h>

// SelfSimilarityProbDistance: tsm[i][j] = mean_{p,q} softplus(a*|X[i,p]-X[j,q]| - b)
// then masked row-softmax of -tsm/TEMP over the valid 448x448 block.
//
// R11: revert R10's fence fusion. Measured: __threadfence (device scope) on
// 8-XCD gfx950 = per-XCD L2 writeback/invalidate; 784 blocks x 2 fences
// serialized the memory system (eval 80 us @ VALUBusy 2.5%). Back to R8's
// fence-free 3-kernel structure (69.4 us), keeping R10's proven-correct wins:
//  - eval lerp via v_dot2_f32_f16: (G0,dG)_f16x2 . (1,frac)_f16x2 + f32 acc
//  - f16-packed (1,frac) staged per feature at build time
// Floor anatomy: 40 us harness ws-poison fill + ~11 us kernels + ~15 us
// node gaps/restore.

#define NTOT 512
#define NV   448
#define DF   64
#define TEMPC 13.544f
#define NG   512
#define TLO  (-6.0f)
#define GH   (12.0f / 512.0f)
#define GINVH (512.0f / 12.0f)

typedef _Float16 h2 __attribute__((ext_vector_type(2)));

__global__ __launch_bounds__(256) void build_kernel(const float* __restrict__ X,
                                                    unsigned int* __restrict__ tabG,
                                                    float2* __restrict__ idxfrac,
                                                    float tpar) {
  const int j = blockIdx.x;          // build rows 0..447 only
  const int tid = threadIdx.x;
  __shared__ float sy[DF];
  __shared__ float sG[NG + 1];
  if (tid < DF) sy[tid] = X[j * DF + tid];
  __syncthreads();

  // exact G_j at 513 grid points: sum_q max(|v - y_q|, t) via v_max3
  for (int k = tid; k <= NG; k += 256) {
    const float v = TLO + (float)k * GH;
    float acc = 0.f;
#pragma unroll 8
    for (int q = 0; q < DF; ++q) {
      const float d = v - sy[q];
      acc += fmaxf(fmaxf(d, -d), tpar);       // v_max3_f32(d,-d,t)
    }
    sG[k] = acc;
  }
  __syncthreads();

  // pack (G0, G[k+1]-G0) as f16x2
  for (int k = tid; k < NG; k += 256) {
    __half2 h = __floats2half2_rn(sG[k], sG[k + 1] - sG[k]);
    tabG[j * NG + k] = *reinterpret_cast<unsigned int*>(&h);
  }

  // per-feature (idx, packed_f16x2(1.0, frac)) for row j as the i-side
  if (tid < DF) {
    const float x = X[j * DF + tid];
    const float u = (fminf(fmaxf(x, TLO), 6.0f) - TLO) * GINVH;
    int idx = (int)u;
    idx = idx > (NG - 2) ? (NG - 2) : idx;
    const float frac = u - (float)idx;
    __half2 pf = __floats2half2_rn(1.0f, frac);
    float pf_bits;
    __builtin_memcpy(&pf_bits, &pf, 4);
    idxfrac[j * DF + tid] = make_float2(__int_as_float(idx), pf_bits);
  }
}

__global__ __launch_bounds__(256, 4) void eval_kernel(const unsigned int* __restrict__ tabG,
                                                      const float2* __restrict__ idxfrac,
                                                      float* __restrict__ sums) {
  const int j0 = blockIdx.x * 16;    // 28 x 28 tiles of 16x16 outputs
  const int i0 = blockIdx.y * 16;

  __shared__ unsigned int sTab[16 * 513];   // 16 j-tables, stride 513 (bank de-alias)
  __shared__ float2 sIF[16][DF];            // i-side (idx, packed(1,frac))

  const int tid = threadIdx.x;
  for (int e = tid; e < 16 * NG; e += 256) {
    const int r = e >> 9, c = e & (NG - 1);
    sTab[r * 513 + c] = tabG[(j0 + r) * NG + c];
  }
  for (int e = tid; e < 16 * DF; e += 256) {
    const int r = e >> 6, c = e & (DF - 1);
    sIF[r][c] = idxfrac[(i0 + r) * DF + c];
  }
  __syncthreads();

  const int tx = tid & 15, ty = tid >> 4;   // output (i0+ty, j0+tx)
  const int tb = tx * 513;
  float acc0 = 0.f, acc1 = 0.f;

#pragma unroll 1
  for (int pc = 0; pc < 4; ++pc) {
    float2 f[16];                            // 16 p's: (idx, packed(1,frac))
#pragma unroll
    for (int k = 0; k < 16; ++k) f[k] = sIF[ty][pc * 16 + k];  // 16-way broadcast
#pragma unroll
    for (int k = 0; k < 16; ++k) {
      const int idx = __float_as_int(f[k].x);
      const unsigned int e = sTab[tb + idx];                   // scattered, de-aliased
      h2 ge, pf;
      __builtin_memcpy(&ge, &e, 4);
      __builtin_memcpy(&pf, &f[k].y, 4);
#if __has_builtin(__builtin_amdgcn_fdot2)
      // G0*1 + dG*frac + acc in ONE v_dot2_f32_f16
      if (k & 1) acc1 = __builtin_amdgcn_fdot2(ge, pf, acc1, false);
      else       acc0 = __builtin_amdgcn_fdot2(ge, pf, acc0, false);
#else
      const float g0 = (float)ge.x, dg = (float)ge.y, fr = (float)pf.y;
      if (k & 1) acc1 += fmaf(fr, dg, g0);
      else       acc0 += fmaf(fr, dg, g0);
#endif
    }
  }
  sums[(i0 + ty) * NTOT + (j0 + tx)] = acc0 + acc1;
}

__global__ __launch_bounds__(256) void softmax_kernel(const float* __restrict__ sums,
                                                      float* __restrict__ Out,
                                                      float scale) {
  const int row = blockIdx.x;
  const int tid = threadIdx.x;
  float* Rp = Out + row * NTOT;
  if (row >= NV) {           // invalid rows: exact zeros
    Rp[tid] = 0.f;
    Rp[tid + 256] = 0.f;
    return;
  }
  const float* Sr = sums + row * NTOT;
  const bool v1 = (tid + 256) < NV;
  const float l0 = Sr[tid] * scale;
  const float l1 = v1 ? Sr[tid + 256] * scale : -3.0e38f;

  __shared__ float redm[4], reds[4];
  float m = fmaxf(l0, l1);
#pragma unroll
  for (int o = 32; o; o >>= 1) m = fmaxf(m, __shfl_xor(m, o));
  if ((tid & 63) == 0) redm[tid >> 6] = m;
  __syncthreads();
  m = fmaxf(fmaxf(redm[0], redm[1]), fmaxf(redm[2], redm[3]));

  const float e0 = __builtin_amdgcn_exp2f(l0 - m);
  const float e1 = v1 ? __builtin_amdgcn_exp2f(l1 - m) : 0.f;
  float s = e0 + e1;
#pragma unroll
  for (int o = 32; o; o >>= 1) s += __shfl_xor(s, o);
  if ((tid & 63) == 0) reds[tid >> 6] = s;
  __syncthreads();
  s = (reds[0] + reds[1]) + (reds[2] + reds[3]);

  const float inv = 1.0f / s;
  Rp[tid] = e0 * inv;
  Rp[tid + 256] = v1 ? e1 * inv : 0.f;
}

extern "C" void kernel_launch(void* const* d_in, const int* in_sizes, int n_in,
                              void* d_out, int out_size, void* d_ws, size_t ws_size,
                              hipStream_t stream) {
  (void)in_sizes; (void)n_in; (void)ws_size; (void)out_size;
  const float* X = (const float*)d_in[0];
  float* Out = (float*)d_out;
  char* ws = (char*)d_ws;

  unsigned int* tabG = (unsigned int*)(ws);                   // 448*512*4 = 896 KB
  float2* idxfrac    = (float2*)(ws + (1u << 20));            // 448*64*8  = 224 KB
  float* sums        = (float*)(ws + (1u << 20) + (1u << 18));// 448*512*4 = 896 KB

  // a = min(elu(4.0335)+1, 100) = 5.0335; b = 14.0885; mask = arange(512) < 448.
  const double a = 5.0335;
  const double b = 14.0885;
  const double LOG2E = 1.4426950408889634;
  const float tpar = (float)(b / a);   // hinge threshold ~2.799
  // tsm = (a/4096)*S + const; uniform parts cancel in the base-2 softmax:
  const float scale = (float)(-a * LOG2E / (4096.0 * (double)TEMPC));

  build_kernel<<<NV, 256, 0, stream>>>(X, tabG, idxfrac, tpar);
  dim3 grid(NV / 16, NV / 16);
  eval_kernel<<<grid, 256, 0, stream>>>(tabG, idxfrac, sums);
  softmax_kernel<<<NTOT, 256, 0, stream>>>(sums, Out, scale);
}